// Round 9
// baseline (1993.352 us; speedup 1.0000x reference)
//
#include <hip/hip_runtime.h>
#include <hip/hip_bf16.h>

// MimiEuclideanCodebook — single bf16-MFMA scan storing per-(row,tile) the
// 8 SMALLEST approx distances (sorted, quantized) + 9th-smallest cover value,
// then np-bit-exact rescore of the provable candidate superset + fused gather.
// Proof: argmin j* has d2a(j*) <= gm + 2*err <= gm + DELTA. If j* in its
// tile's top-8, the floor-quantized value deq <= actual <= thr keeps it.
// Else the 9th-smallest C <= d2a(j*) <= thr forces a full rescan of that tile.
// All decisions via round-4-verified np-exact fp32 FMA chain, lex-(val,idx).

typedef float f32x4 __attribute__((ext_vector_type(4)));
typedef short s16x4 __attribute__((ext_vector_type(4)));
typedef short s16x8 __attribute__((ext_vector_type(8)));

#define D_DIM 256
#define N_ROWS 65536
#define K_CODES 2048
#define VQ_EPS 1e-5f
#define DELTA 1.0f
#define QSCALE (255.0f / DELTA)
#define DQSCALE (DELTA / 255.0f)

__device__ __forceinline__ short bf16s(float f) {
    __hip_bfloat16 h = __float2bfloat16(f);
    return __builtin_bit_cast(short, h);
}

// ---------------- prep: embed = embed_sum / clip(usage) -----------------------
__global__ void prep_embed(const float* __restrict__ es, const float* __restrict__ us,
                           float* __restrict__ embed) {
    int i = blockIdx.x * 256 + threadIdx.x;               // 524288
    int k = i >> 8;
    float u = fmaxf(us[k], VQ_EPS);
    embed[i] = es[i] / u;                                 // IEEE div == np bitwise
}

// numpy pairwise sum of squares over 256 (verified round 4)
__device__ __forceinline__ void np_sumsq_16lane(const float* a, float* out, int g) {
#pragma clang fp contract(off)
    int j = g & 7, h = g >> 3;
    const float* p = a + h * 128;
    float t = p[j];
    float r = t * t;
#pragma unroll
    for (int i = 1; i < 16; ++i) { float v = p[j + 8 * i]; r += v * v; }
    r += __shfl_xor(r, 1);
    r += __shfl_xor(r, 2);
    r += __shfl_xor(r, 4);
    float other = __shfl_xor(r, 8);
    if (g == 0) *out = r + other;
}

__global__ void prep_e2(const float* __restrict__ embed, float* __restrict__ e2) {
    int gid = blockIdx.x * 256 + threadIdx.x;             // 2048 * 16
    int k = gid >> 4;
    np_sumsq_16lane(embed + k * D_DIM, e2 + k, threadIdx.x & 15);
}

__global__ void prep_x2(const float* __restrict__ x, float* __restrict__ x2) {
    int gid = blockIdx.x * 256 + threadIdx.x;             // 65536 * 16
    int r = gid >> 4;
    np_sumsq_16lane(x + r * D_DIM, x2 + r, threadIdx.x & 15);
}

// --------- bf16 MFMA scan: per-(row,tile) tilemin + sorted top-8 + cover ------
// Wave layout: each wave owns 32 rows x full 128-col tile (acc[2][8]).
__launch_bounds__(256, 2)
__global__ void vq_scan(const float* __restrict__ x, const float* __restrict__ embed,
                        const float* __restrict__ e2, const float* __restrict__ x2,
                        float* __restrict__ tilemin, unsigned short* __restrict__ packs,
                        unsigned char* __restrict__ coffs) {
    __shared__ short lA[128][40];                         // bf16 bits, stride 40
    __shared__ short lB[128][40];

    const int mt = blockIdx.x >> 4, nt = blockIdx.x & 15;
    const int m_base = mt * 128, n_base = nt * 128;
    const int tid = threadIdx.x, lane = tid & 63, wid = tid >> 6;
    const int rb = wid * 32;                              // wave: rows rb..rb+31
    const int l15 = lane & 15, lg = lane >> 4;
    const int srow = tid >> 1, sseg = tid & 1;            // staging: row, 16-float half

    f32x4 acc[2][8];
#pragma unroll
    for (int m = 0; m < 2; ++m)
#pragma unroll
        for (int n = 0; n < 8; ++n) { f32x4 z = {0.f, 0.f, 0.f, 0.f}; acc[m][n] = z; }

    f32x4 rA[4], rB[4];
    auto gload = [&](int kc) {
#pragma unroll
        for (int v = 0; v < 4; ++v)
            rA[v] = *(const f32x4*)&x[(m_base + srow) * D_DIM + kc * 32 + sseg * 16 + v * 4];
#pragma unroll
        for (int v = 0; v < 4; ++v)
            rB[v] = *(const f32x4*)&embed[(n_base + srow) * D_DIM + kc * 32 + sseg * 16 + v * 4];
    };
    auto swrite = [&]() {
#pragma unroll
        for (int v = 0; v < 4; ++v) {
            s16x4 a, b;
#pragma unroll
            for (int j = 0; j < 4; ++j) { a[j] = bf16s(rA[v][j]); b[j] = bf16s(rB[v][j]); }
            *(s16x4*)&lA[srow][sseg * 16 + v * 4] = a;
            *(s16x4*)&lB[srow][sseg * 16 + v * 4] = b;
        }
    };
    auto compute = [&]() {
        s16x8 af[2], bf[8];
#pragma unroll
        for (int m = 0; m < 2; ++m)
            af[m] = *(const s16x8*)&lA[rb + m * 16 + l15][lg * 8];
#pragma unroll
        for (int n = 0; n < 8; ++n)
            bf[n] = *(const s16x8*)&lB[n * 16 + l15][lg * 8];
#pragma unroll
        for (int m = 0; m < 2; ++m)
#pragma unroll
            for (int n = 0; n < 8; ++n)
                acc[m][n] = __builtin_amdgcn_mfma_f32_16x16x32_bf16(af[m], bf[n], acc[m][n], 0, 0, 0);
    };

    gload(0);
#pragma unroll 1
    for (int kc = 0; kc < 8; ++kc) {
        __syncthreads();                                  // prev compute done
        swrite();
        __syncthreads();                                  // LDS visible
        if (kc < 7) gload(kc + 1);
        compute();
    }

    // epilogue: d2a = (x2 - 2*xe_a) + e2; per row select 8 smallest (sorted,
    // lex-(val,code) deterministic) + 9th-smallest cover. No atomics.
    // C/D layout (m89-verified): col = lane&15 (+n*16), row = lg*4 + j (+m*16)
    const int grow0 = m_base + rb + lg * 4;
    float e2v[8];
#pragma unroll
    for (int n = 0; n < 8; ++n) e2v[n] = e2[n_base + n * 16 + l15];

#pragma unroll
    for (int m = 0; m < 2; ++m) {
#pragma unroll
        for (int j = 0; j < 4; ++j) {
            int gr = grow0 + m * 16 + j;
            float x2v = x2[gr];
            float d2v[8];
            float mn = __builtin_inff();
#pragma unroll
            for (int n = 0; n < 8; ++n) {
                d2v[n] = (x2v - 2.0f * acc[m][n][j]) + e2v[n];
                mn = fminf(mn, d2v[n]);
            }
#pragma unroll
            for (int s = 1; s < 16; s <<= 1) mn = fminf(mn, __shfl_xor(mn, s));
            int tbase = (gr * 16 + nt) * 8;
#pragma unroll
            for (int i = 0; i < 9; ++i) {
                float lv = d2v[0]; int ln = 0;            // local min (lowest n wins ties)
#pragma unroll
                for (int n = 1; n < 8; ++n)
                    if (d2v[n] < lv) { lv = d2v[n]; ln = n; }
                int lc = ln * 16 + l15;                   // code within tile
#pragma unroll
                for (int s = 1; s < 16; s <<= 1) {        // 16-lane lex min (val, code)
                    float ov = __shfl_xor(lv, s);
                    int oc = __shfl_xor(lc, s);
                    if (ov < lv || (ov == lv && oc < lc)) { lv = ov; lc = oc; }
                }
                int offq = (int)((lv - mn) * QSCALE);     // floor-quant (>=0)
                offq = offq > 255 ? 255 : offq;
                if (i < 8) {
                    if (l15 == (lc & 15)) {               // owner consumes + stores
                        d2v[lc >> 4] = __builtin_inff();
                        packs[tbase + i] = (unsigned short)(lc | (offq << 8));
                    }
                } else if (l15 == 0) {
                    coffs[gr * 16 + nt] = (unsigned char)offq;
                }
            }
            if (l15 == 0) tilemin[gr * 16 + nt] = mn;
        }
    }
}

// ------- np-exact rescore: value-filtered candidates + rare tile rescan -------
__launch_bounds__(256, 4)
__global__ void vq_rescore(const float* __restrict__ x, const float* __restrict__ embed,
                           const float* __restrict__ e2, const float* __restrict__ x2,
                           const float* __restrict__ tilemin,
                           const unsigned short* __restrict__ packs,
                           const unsigned char* __restrict__ coffs,
                           const float* __restrict__ es, const float* __restrict__ us,
                           float* __restrict__ out) {
    __shared__ unsigned short list[4][128];
    const int tid = threadIdx.x, w = tid >> 6, lane = tid & 63;
    const int r = blockIdx.x * 4 + w;

    // global approx min over 16 tile minima (16-lane groups, replicated)
    float gm = tilemin[r * 16 + (lane & 15)];
#pragma unroll
    for (int s = 1; s < 16; s <<= 1) gm = fminf(gm, __shfl_xor(gm, s));
    const float thr = gm + DELTA;

    // lane covers tile t = lane>>2, slots (lane&3) and (lane&3)+4
    const int t = lane >> 2, s0 = lane & 3, s1 = (lane & 3) + 4;
    const float tmt = tilemin[r * 16 + t];
    const bool qual = (tmt <= thr);
    unsigned short p0 = packs[(r * 16 + t) * 8 + s0];
    unsigned short p1 = packs[(r * 16 + t) * 8 + s1];
    bool v0 = qual && (tmt + (float)(p0 >> 8) * DQSCALE <= thr);
    bool v1 = qual && (tmt + (float)(p1 >> 8) * DQSCALE <= thr);
    unsigned long long b0 = __ballot(v0), b1 = __ballot(v1);
    unsigned long long lt = (1ull << lane) - 1ull;
    int n0 = __popcll(b0);
    int ncand = n0 + __popcll(b1);
    if (v0) list[w][__popcll(b0 & lt)] = (unsigned short)(t * 128 + (p0 & 0xFF));
    if (v1) list[w][n0 + __popcll(b1 & lt)] = (unsigned short)(t * 128 + (p1 & 0xFF));
    // tiles needing full rescan: 9th-smallest cover <= thr
    bool rs = qual && ((lane & 3) == 0) &&
              (tmt + (float)coffs[r * 16 + t] * DQSCALE <= thr);
    unsigned long long ovb = __ballot(rs);
    __syncthreads();

    float bv = __builtin_inff();
    int bi = 0x7FFFFFFF;
    const float x2v = x2[r];

    auto dot_d2 = [&](int code) -> float {
        float tt = 0.0f;
#pragma unroll 8
        for (int k4 = 0; k4 < 64; ++k4) {                 // single chain, k ascending
            f32x4 a4 = *(const f32x4*)&x[r * D_DIM + k4 * 4];
            f32x4 e4 = *(const f32x4*)&embed[code * D_DIM + k4 * 4];
            tt = __builtin_fmaf(a4[0], e4[0], tt);
            tt = __builtin_fmaf(a4[1], e4[1], tt);
            tt = __builtin_fmaf(a4[2], e4[2], tt);
            tt = __builtin_fmaf(a4[3], e4[3], tt);
        }
        return (x2v - 2.0f * tt) + e2[code];              // np op order
    };
    auto lexmin = [&](float d2, int code) {
        if (d2 < bv || (d2 == bv && code < bi)) { bv = d2; bi = code; }
    };

    for (int idx = lane; idx < ncand; idx += 64) {
        int code = (int)list[w][idx];
        lexmin(dot_d2(code), code);
    }
    unsigned long long mrem = ovb;
    while (mrem) {                                        // rare full-tile rescans
        int b = __ffsll(mrem) - 1; mrem &= mrem - 1;
        int t2 = b >> 2;
        lexmin(dot_d2(t2 * 128 + lane), t2 * 128 + lane);
        lexmin(dot_d2(t2 * 128 + 64 + lane), t2 * 128 + 64 + lane);
    }
#pragma unroll
    for (int s = 1; s < 64; s <<= 1) {                    // 64-lane lex allreduce
        float ov = __shfl_xor(bv, s);
        int oi = __shfl_xor(bi, s);
        if (ov < bv || (ov == bv && oi < bi)) { bv = ov; bi = oi; }
    }
    if (lane == 0) out[r] = (float)bi;

    // fused gather: quantized[r] = es[bi]/max(us[bi],eps); 64 lanes x 4 cols
    float u = fmaxf(us[bi], VQ_EPS);
    f32x4 wv = *(const f32x4*)&es[bi * D_DIM + lane * 4];
    f32x4 o;
#pragma unroll
    for (int j = 0; j < 4; ++j) o[j] = wv[j] / u;         // IEEE div == np bitwise
    *(f32x4*)&out[N_ROWS + r * D_DIM + lane * 4] = o;
}

extern "C" void kernel_launch(void* const* d_in, const int* in_sizes, int n_in,
                              void* d_out, int out_size, void* d_ws, size_t ws_size,
                              hipStream_t stream) {
    const float* x = (const float*)d_in[0];               // [65536, 256]
    const float* es = (const float*)d_in[1];              // [2048, 256]
    const float* us = (const float*)d_in[2];              // [2048]
    float* out = (float*)d_out;

    char* w = (char*)d_ws;                                // total 24,387,584 B
    float* embed          = (float*)(w);                  //  2,097,152
    float* e2             = (float*)(w + 2097152);        //      8,192
    float* x2             = (float*)(w + 2105344);        //    262,144
    float* tilemin        = (float*)(w + 2367488);        //  4,194,304
    unsigned short* packs = (unsigned short*)(w + 6561792);// 16,777,216
    unsigned char* coffs  = (unsigned char*)(w + 23339008);// 1,048,576

    hipLaunchKernelGGL(prep_embed, dim3(2048), dim3(256), 0, stream, es, us, embed);
    hipLaunchKernelGGL(prep_e2, dim3(128), dim3(256), 0, stream, embed, e2);
    hipLaunchKernelGGL(prep_x2, dim3(4096), dim3(256), 0, stream, x, x2);
    hipLaunchKernelGGL(vq_scan, dim3(8192), dim3(256), 0, stream,
                       x, embed, e2, x2, tilemin, packs, coffs);
    hipLaunchKernelGGL(vq_rescore, dim3(16384), dim3(256), 0, stream,
                       x, embed, e2, x2, tilemin, packs, coffs, es, us, out);
}

// Round 10
// 310.307 us; speedup vs baseline: 6.4238x; 6.4238x over previous
//
#include <hip/hip_runtime.h>
#include <hip/hip_bf16.h>

// MimiEuclideanCodebook — round-6 architecture, optimized:
// pass0: bf16-MFMA GEMM -> per-row global lex-min (u64 atomicMin key).
// pass1: same GEMM -> capture codes with d2a <= gm + DELTA (global threshold;
//        low density ~2-3/row), atomicAdd slots (order-independent rescore).
// rescore: np-exact fp32 FMA-chain dots on candidates, 8 lanes/row, lex-min,
//        fused gather. Fallback (cnt > SLOTS): full exact scan (never fires).
// GEMM staging: x/embed pre-converted to bf16 with bank-swizzle pre-permuted
// (slot ^= (row>>1)&3 per 64B row) -> global_load_lds(16B) linear dest +
// swizzled ds_read_b128 (conflict-free), double-buffered, XCD-swizzled grid.

typedef float f32x4 __attribute__((ext_vector_type(4)));
typedef short s16x8 __attribute__((ext_vector_type(8)));

#define D_DIM 256
#define N_ROWS 65536
#define K_CODES 2048
#define VQ_EPS 1e-5f
#define DELTA 0.5f
#define SLOTS 24

__device__ __forceinline__ short bf16s(float f) {
    __hip_bfloat16 h = __float2bfloat16(f);
    return __builtin_bit_cast(short, h);
}
__device__ __forceinline__ unsigned fkey(float f) {       // order-preserving u32
    unsigned u = __float_as_uint(f);
    return (u & 0x80000000u) ? ~u : (u | 0x80000000u);
}
__device__ __forceinline__ float funkey(unsigned k) {
    unsigned u = (k & 0x80000000u) ? (k ^ 0x80000000u) : ~k;
    return __uint_as_float(u);
}
__device__ __forceinline__ void gload16(const void* g, void* l) {
    __builtin_amdgcn_global_load_lds(
        (const __attribute__((address_space(1))) void*)g,
        (__attribute__((address_space(3))) void*)l, 16, 0, 0);
}

// ---------------- prep: embed = embed_sum / clip(usage) -----------------------
__global__ void prep_embed(const float* __restrict__ es, const float* __restrict__ us,
                           float* __restrict__ embed) {
    int i = blockIdx.x * 256 + threadIdx.x;               // 524288
    int k = i >> 8;
    float u = fmaxf(us[k], VQ_EPS);
    embed[i] = es[i] / u;                                 // IEEE div == np bitwise
}

// bf16 convert + swizzle-permute: dst[r][kc][s] = src[r][kc*32 + (s^((r>>1)&3))*8 ..]
template <int ROWS>
__global__ void prep_swz(const float* __restrict__ src, unsigned short* __restrict__ dst) {
    int gid = blockIdx.x * 256 + threadIdx.x;             // ROWS*32 threads
    int r = gid >> 5, idx = gid & 31;
    int kc = idx >> 2, s = idx & 3;
    int k0 = kc * 32 + (s ^ ((r >> 1) & 3)) * 8;
    const float* p = src + r * D_DIM + k0;
    s16x8 v;
#pragma unroll
    for (int j = 0; j < 8; ++j) v[j] = bf16s(p[j]);
    *(s16x8*)&dst[r * 256 + kc * 32 + s * 8] = v;
}

// numpy pairwise sum of squares over 256 (verified round 4)
__device__ __forceinline__ void np_sumsq_16lane(const float* a, float* out, int g) {
#pragma clang fp contract(off)
    int j = g & 7, h = g >> 3;
    const float* p = a + h * 128;
    float t = p[j];
    float r = t * t;
#pragma unroll
    for (int i = 1; i < 16; ++i) { float v = p[j + 8 * i]; r += v * v; }
    r += __shfl_xor(r, 1);
    r += __shfl_xor(r, 2);
    r += __shfl_xor(r, 4);
    float other = __shfl_xor(r, 8);
    if (g == 0) *out = r + other;
}

__global__ void prep_e2(const float* __restrict__ embed, float* __restrict__ e2) {
    int gid = blockIdx.x * 256 + threadIdx.x;             // 2048 * 16
    int k = gid >> 4;
    np_sumsq_16lane(embed + k * D_DIM, e2 + k, threadIdx.x & 15);
}

__global__ void prep_x2(const float* __restrict__ x, float* __restrict__ x2,
                        unsigned long long* __restrict__ rowmin,
                        unsigned* __restrict__ counts) {
    int gid = blockIdx.x * 256 + threadIdx.x;             // 65536 * 16
    int r = gid >> 4;
    int g = threadIdx.x & 15;
    np_sumsq_16lane(x + r * D_DIM, x2 + r, g);
    if (g == 1) rowmin[r] = 0xFFFFFFFFFFFFFFFFull;
    if (g == 2) counts[r] = 0u;
}

// ------ bf16 MFMA scan: PASS=0 global rowmin key, PASS=1 capture candidates ---
template <int PASS>
__launch_bounds__(256, 2)
__global__ void vq_scan(const unsigned short* __restrict__ xswz,
                        const unsigned short* __restrict__ eswz,
                        const float* __restrict__ e2, const float* __restrict__ x2,
                        unsigned long long* __restrict__ rowmin,
                        unsigned* __restrict__ counts,
                        unsigned short* __restrict__ cands) {
    __shared__ __align__(16) short lds[2][2][4096];       // [buf][A/B][8KB]

    const int bid = blockIdx.x;
    const int swz = (bid & 7) * 1024 + (bid >> 3);        // XCD-contiguous tiles
    const int mt = swz >> 4, nt = swz & 15;
    const int m_base = mt * 128, n_base = nt * 128;
    const int tid = threadIdx.x, lane = tid & 63, wid = tid >> 6;
    const int rb = wid * 32;                              // wave: rows rb..rb+31
    const int l15 = lane & 15, lg = lane >> 4;

    f32x4 acc[2][8];
#pragma unroll
    for (int m = 0; m < 2; ++m)
#pragma unroll
        for (int n = 0; n < 8; ++n) { f32x4 z = {0.f, 0.f, 0.f, 0.f}; acc[m][n] = z; }

    auto stage = [&](int buf, int kc) {
#pragma unroll
        for (int i = 0; i < 2; ++i) {
            int off = i * 4096 + wid * 1024 + lane * 16;  // linear LDS dest bytes
            int row = off >> 6, slot = (off >> 4) & 3;    // pre-permuted source
            gload16((const char*)xswz + (((size_t)(m_base + row)) << 9) + (kc << 6) + (slot << 4),
                    (char*)&lds[buf][0][0] + off);
            gload16((const char*)eswz + (((size_t)(n_base + row)) << 9) + (kc << 6) + (slot << 4),
                    (char*)&lds[buf][1][0] + off);
        }
    };
    auto compute = [&](int buf) {
        const short* A = &lds[buf][0][0];
        const short* B = &lds[buf][1][0];
        s16x8 af[2], bf[8];
#pragma unroll
        for (int m = 0; m < 2; ++m) {
            int R = rb + m * 16 + l15, s = lg ^ ((R >> 1) & 3);
            af[m] = *(const s16x8*)&A[R * 32 + s * 8];
        }
#pragma unroll
        for (int n = 0; n < 8; ++n) {
            int R = n * 16 + l15, s = lg ^ ((R >> 1) & 3);
            bf[n] = *(const s16x8*)&B[R * 32 + s * 8];
        }
#pragma unroll
        for (int m = 0; m < 2; ++m)
#pragma unroll
            for (int n = 0; n < 8; ++n)
                acc[m][n] = __builtin_amdgcn_mfma_f32_16x16x32_bf16(af[m], bf[n], acc[m][n], 0, 0, 0);
    };

    stage(0, 0);
    __syncthreads();
#pragma unroll 1
    for (int kc = 0; kc < 8; ++kc) {
        if (kc < 7) stage((kc + 1) & 1, kc + 1);          // loads fly under compute
        compute(kc & 1);
        __syncthreads();                                  // drain gload + readers done
    }

    // epilogue: d2a = (x2 - 2*xe_a) + e2
    // C/D layout (round-8 verified): col = n*16 + l15, row = lg*4 + j (+m*16)
    const int grow0 = m_base + rb + lg * 4;
    float e2v[8];
#pragma unroll
    for (int n = 0; n < 8; ++n) e2v[n] = e2[n_base + n * 16 + l15];

#pragma unroll
    for (int m = 0; m < 2; ++m) {
#pragma unroll
        for (int j = 0; j < 4; ++j) {
            int gr = grow0 + m * 16 + j;
            float x2v = x2[gr];
            if (PASS == 0) {
                float bv = __builtin_inff(); int bc = 0x7FFFFFFF;
#pragma unroll
                for (int n = 0; n < 8; ++n) {
                    float d2 = (x2v - 2.0f * acc[m][n][j]) + e2v[n];
                    int code = n_base + n * 16 + l15;
                    if (d2 < bv) { bv = d2; bc = code; }  // ascending code per lane
                }
#pragma unroll
                for (int s = 1; s < 16; s <<= 1) {        // 16-lane lex min
                    float ov = __shfl_xor(bv, s);
                    int oc = __shfl_xor(bc, s);
                    if (ov < bv || (ov == bv && oc < bc)) { bv = ov; bc = oc; }
                }
                if (l15 == 0) {
                    unsigned long long key = ((unsigned long long)fkey(bv) << 32) | (unsigned)bc;
                    atomicMin(&rowmin[gr], key);
                }
            } else {
                float thr = funkey((unsigned)(rowmin[gr] >> 32)) + DELTA;
#pragma unroll
                for (int n = 0; n < 8; ++n) {
                    float d2 = (x2v - 2.0f * acc[m][n][j]) + e2v[n];
                    if (d2 <= thr) {
                        unsigned p = atomicAdd(&counts[gr], 1u);
                        if (p < SLOTS)
                            cands[gr * SLOTS + p] = (unsigned short)(n_base + n * 16 + l15);
                    }
                }
            }
        }
    }
}

// ------- np-exact rescore (8 lanes/row, 32 rows/block) + fused gather ---------
__launch_bounds__(256, 4)
__global__ void vq_rescore(const float* __restrict__ x, const float* __restrict__ embed,
                           const float* __restrict__ e2, const float* __restrict__ x2,
                           const unsigned* __restrict__ counts,
                           const unsigned short* __restrict__ cands,
                           const float* __restrict__ es, const float* __restrict__ us,
                           float* __restrict__ out) {
    const int tid = threadIdx.x;
    const int r = blockIdx.x * 32 + (tid >> 3);
    const int sl = tid & 7;
    const unsigned cnt = counts[r];
    const float x2v = x2[r];

    float bv = __builtin_inff();
    int bi = 0x7FFFFFFF;

    auto dot_d2 = [&](int code) -> float {
        float t = 0.0f;
#pragma unroll 8
        for (int k4 = 0; k4 < 64; ++k4) {                 // single chain, k ascending
            f32x4 a4 = *(const f32x4*)&x[r * D_DIM + k4 * 4];
            f32x4 e4 = *(const f32x4*)&embed[code * D_DIM + k4 * 4];
            t = __builtin_fmaf(a4[0], e4[0], t);
            t = __builtin_fmaf(a4[1], e4[1], t);
            t = __builtin_fmaf(a4[2], e4[2], t);
            t = __builtin_fmaf(a4[3], e4[3], t);
        }
        return (x2v - 2.0f * t) + e2[code];               // np op order
    };
    auto lexmin = [&](float d2, int code) {
        if (d2 < bv || (d2 == bv && code < bi)) { bv = d2; bi = code; }
    };

    if (cnt <= SLOTS) {
        for (int slot = sl; slot < (int)cnt; slot += 8) {
            int code = (int)cands[r * SLOTS + slot];
            lexmin(dot_d2(code), code);
        }
    } else {
#pragma unroll 1
        for (int q = 0; q < 256; ++q) {                   // fallback: exact full scan
            int code = q * 8 + sl;
            lexmin(dot_d2(code), code);
        }
    }
#pragma unroll
    for (int s = 1; s < 8; s <<= 1) {                     // 8-lane lex allreduce
        float ov = __shfl_xor(bv, s);
        int oi = __shfl_xor(bi, s);
        if (ov < bv || (ov == bv && oi < bi)) { bv = ov; bi = oi; }
    }
    if (sl == 0) out[r] = (float)bi;

    // fused gather: quantized[r] = es[bi]/max(us[bi],eps); 8 lanes x 32 floats
    float u = fmaxf(us[bi], VQ_EPS);
    float* outq = out + N_ROWS;
#pragma unroll
    for (int v = 0; v < 8; ++v) {
        f32x4 w = *(const f32x4*)&es[bi * D_DIM + sl * 32 + v * 4];
        f32x4 o;
#pragma unroll
        for (int j = 0; j < 4; ++j) o[j] = w[j] / u;      // IEEE div == np bitwise
        *(f32x4*)&outq[r * D_DIM + sl * 32 + v * 4] = o;
    }
}

extern "C" void kernel_launch(void* const* d_in, const int* in_sizes, int n_in,
                              void* d_out, int out_size, void* d_ws, size_t ws_size,
                              hipStream_t stream) {
    const float* x = (const float*)d_in[0];               // [65536, 256]
    const float* es = (const float*)d_in[1];              // [2048, 256]
    const float* us = (const float*)d_in[2];              // [2048]
    float* out = (float*)d_out;

    char* w = (char*)d_ws;                                // total 40,902,656 B
    unsigned short* xswz  = (unsigned short*)(w);                 // 33,554,432
    unsigned short* eswz  = (unsigned short*)(w + 33554432);      //  1,048,576
    float* embed          = (float*)(w + 34603008);               //  2,097,152
    float* e2             = (float*)(w + 36700160);               //      8,192
    float* x2             = (float*)(w + 36708352);               //    262,144
    unsigned long long* rowmin = (unsigned long long*)(w + 36970496); // 524,288
    unsigned* counts      = (unsigned*)(w + 37494784);            //    262,144
    unsigned short* cands = (unsigned short*)(w + 37756928);      //  3,145,728

    hipLaunchKernelGGL(prep_embed, dim3(2048), dim3(256), 0, stream, es, us, embed);
    hipLaunchKernelGGL((prep_swz<K_CODES>), dim3(256), dim3(256), 0, stream, embed, eswz);
    hipLaunchKernelGGL(prep_e2, dim3(128), dim3(256), 0, stream, embed, e2);
    hipLaunchKernelGGL(prep_x2, dim3(4096), dim3(256), 0, stream, x, x2, rowmin, counts);
    hipLaunchKernelGGL((prep_swz<N_ROWS>), dim3(8192), dim3(256), 0, stream, x, xswz);
    hipLaunchKernelGGL((vq_scan<0>), dim3(8192), dim3(256), 0, stream,
                       xswz, eswz, e2, x2, rowmin, counts, cands);
    hipLaunchKernelGGL((vq_scan<1>), dim3(8192), dim3(256), 0, stream,
                       xswz, eswz, e2, x2, rowmin, counts, cands);
    hipLaunchKernelGGL(vq_rescore, dim3(2048), dim3(256), 0, stream,
                       x, embed, e2, x2, counts, cands, es, us, out);
}